// Round 1
// baseline (218.103 us; speedup 1.0000x reference)
//
#include <hip/hip_runtime.h>
#include <stdint.h>

#define NEAR_PLANE 0.0001f
#define MIN_COV    0.0001f
#define SIGMA_RAD  3.0f
#define ALPHA_MAX  0.999f

// 64-byte per-gaussian param block (16 floats) for clean float4 staging.
struct GParam {
    float mx, my;          // 0,1  projected center
    float ia, ib, ic;      // 2,3,4 inverse 2D covariance (c/det, -b/det, a/det)
    float op;              // 5    opacity (0 if not overlapping)
    float r, g, b;         // 6,7,8 color
    float minx, maxx;      // 9,10 bbox
    float miny, maxy;      // 11,12
    float pad0, pad1, pad2;
};

__global__ void gs_prep(const float* __restrict__ means,
                        const float* __restrict__ covs,
                        const float* __restrict__ colors,
                        const float* __restrict__ opac,
                        const float* __restrict__ K,
                        const float* __restrict__ c2w,
                        const int* __restrict__ hp, const int* __restrict__ wp,
                        GParam* __restrict__ params,
                        unsigned long long* __restrict__ keys,
                        int N) {
    int i = blockIdx.x * blockDim.x + threadIdx.x;
    if (i >= N) return;
    float Wf = (float)(*wp), Hf = (float)(*hp);

    // R = c2w[:3,:3]^T, t = -R @ c2w[:3,3]   (c2w row-major 4x4)
    float R[3][3];
    #pragma unroll
    for (int r = 0; r < 3; ++r)
        #pragma unroll
        for (int c = 0; c < 3; ++c)
            R[r][c] = c2w[c * 4 + r];
    float ct0 = c2w[3], ct1 = c2w[7], ct2 = c2w[11];
    float t0 = -(R[0][0]*ct0 + R[0][1]*ct1 + R[0][2]*ct2);
    float t1 = -(R[1][0]*ct0 + R[1][1]*ct1 + R[1][2]*ct2);
    float t2 = -(R[2][0]*ct0 + R[2][1]*ct1 + R[2][2]*ct2);

    float m0 = means[i*3+0], m1 = means[i*3+1], m2 = means[i*3+2];
    float x = R[0][0]*m0 + R[0][1]*m1 + R[0][2]*m2 + t0;
    float y = R[1][0]*m0 + R[1][1]*m1 + R[1][2]*m2 + t1;
    float z = R[2][0]*m0 + R[2][1]*m1 + R[2][2]*m2 + t2;

    // covc = R C R^T
    const float* C = covs + i * 9;
    float M[3][3], CC[3][3];
    #pragma unroll
    for (int r = 0; r < 3; ++r)
        #pragma unroll
        for (int c = 0; c < 3; ++c)
            M[r][c] = R[r][0]*C[0*3+c] + R[r][1]*C[1*3+c] + R[r][2]*C[2*3+c];
    #pragma unroll
    for (int r = 0; r < 3; ++r)
        #pragma unroll
        for (int c = 0; c < 3; ++c)
            CC[r][c] = M[r][0]*R[c][0] + M[r][1]*R[c][1] + M[r][2]*R[c][2];

    bool vis = z > NEAR_PLANE;
    float sz = vis ? z : 1.0f;
    float fx = K[0], fy = K[4], cx = K[2], cy = K[5];
    float mx = fx * x / sz + cx;
    float my = fy * y / sz + cy;

    // J rows: J0 = (a0, 0, a2), J1 = (0, b1, b2)
    float a0 = fx / sz, a2 = -fx * x / (sz * sz);
    float b1 = fy / sz, b2 = -fy * y / (sz * sz);
    // u = J0 * CC ; v = J1 * CC
    float u0 = a0*CC[0][0] + a2*CC[2][0];
    float u1 = a0*CC[0][1] + a2*CC[2][1];
    float u2 = a0*CC[0][2] + a2*CC[2][2];
    float v1 = b1*CC[1][1] + b2*CC[2][1];
    float v2 = b1*CC[1][2] + b2*CC[2][2];
    float a = u0*a0 + u2*a2 + MIN_COV;   // cov2[0][0]
    float b = u1*b1 + u2*b2;             // cov2[0][1]
    float c = v1*b1 + v2*b2 + MIN_COV;   // cov2[1][1]

    float disc = sqrtf(fmaxf((a - c)*(a - c) + 4.0f*b*b, 0.0f));
    float lam  = fmaxf(0.5f*(a + c + disc), MIN_COV);
    float rad  = SIGMA_RAD * sqrtf(lam);
    float minx = floorf(mx - rad), maxx = ceilf(mx + rad);
    float miny = floorf(my - rad), maxy = ceilf(my + rad);
    bool overlap = vis && (maxx >= 0.0f) && (minx < Wf) && (maxy >= 0.0f) && (miny < Hf);

    float det = fmaxf(a*c - b*b, 1e-12f);
    GParam p;
    p.mx = mx; p.my = my;
    p.ia = c / det; p.ib = -b / det; p.ic = a / det;
    p.op = overlap ? opac[i] : 0.0f;
    p.r = colors[i*3+0]; p.g = colors[i*3+1]; p.b = colors[i*3+2];
    if (overlap) { p.minx = minx; p.maxx = maxx; p.miny = miny; p.maxy = maxy; }
    else         { p.minx = 1e30f; p.maxx = -1e30f; p.miny = 1e30f; p.maxy = -1e30f; }
    p.pad0 = p.pad1 = p.pad2 = 0.0f;
    params[i] = p;

    unsigned int zb = overlap ? __float_as_uint(z) : 0x7F800000u; // +inf for culled
    keys[i] = ((unsigned long long)zb << 32) | (unsigned int)i;
}

// One block of 1024 threads: bitonic sort keys (z-bits<<32 | idx), count
// finite keys, gather params into depth order.
__global__ void gs_sort_gather(const GParam* __restrict__ params,
                               const unsigned long long* __restrict__ keys,
                               GParam* __restrict__ sorted,
                               int* __restrict__ countp) {
    __shared__ unsigned long long sk[1024];
    int tid = threadIdx.x;
    sk[tid] = keys[tid];
    __syncthreads();
    for (int k = 2; k <= 1024; k <<= 1) {
        for (int j = k >> 1; j > 0; j >>= 1) {
            int ixj = tid ^ j;
            if (ixj > tid) {
                unsigned long long A = sk[tid], B = sk[ixj];
                bool up = (tid & k) == 0;
                if ((A > B) == up) { sk[tid] = B; sk[ixj] = A; }
            }
            __syncthreads();
        }
    }
    unsigned long long key = sk[tid];
    int finite = ((unsigned int)(key >> 32)) < 0x7F800000u ? 1 : 0;
    int cnt = __syncthreads_count(finite);
    if (tid == 0) *countp = cnt;
    unsigned int idx = (unsigned int)(key & 0xFFFFFFFFu);
    const float4* src = (const float4*)(params + idx);
    float4*       dst = (float4*)(sorted + tid);
    dst[0] = src[0]; dst[1] = src[1]; dst[2] = src[2]; dst[3] = src[3];
}

#define CHUNK 256

__global__ __launch_bounds__(256) void gs_render(const GParam* __restrict__ sorted,
                                                 const int* __restrict__ countp,
                                                 const int* __restrict__ hp,
                                                 const int* __restrict__ wp,
                                                 float* __restrict__ out) {
    __shared__ float4 sg[CHUNK * 4];
    int W = *wp, H = *hp;
    int pix = blockIdx.x * 256 + threadIdx.x;
    bool active = pix < W * H;
    int px = active ? (pix % W) : 0;
    int py = active ? (pix / W) : 0;
    float fpx = (float)px, fpy = (float)py;

    float T = 1.0f, accr = 0.0f, accg = 0.0f, accb = 0.0f;
    int n = *countp;
    bool done = !active;

    for (int base = 0; base < n; base += CHUNK) {
        int cnt = min(CHUNK, n - base);
        __syncthreads();
        const float4* src = (const float4*)(sorted + base);
        for (int j = threadIdx.x; j < cnt * 4; j += 256) sg[j] = src[j];
        __syncthreads();
        if (!done) {
            const float* s = (const float*)sg;
            for (int gi = 0; gi < cnt; ++gi) {
                const float* p = s + gi * 16;
                if (fpx < p[9] || fpx > p[10] || fpy < p[11] || fpy > p[12]) continue;
                float dx = fpx - p[0], dy = fpy - p[1];
                float q = p[2]*dx*dx + 2.0f*p[3]*dx*dy + p[4]*dy*dy;
                float w = __expf(-0.5f * q);
                float alpha = fminf(p[5] * w, ALPHA_MAX);
                float at = alpha * T;
                accr += at * p[6]; accg += at * p[7]; accb += at * p[8];
                T *= (1.0f - alpha);
                if (T < 1e-6f) { done = true; break; }
            }
        }
    }
    if (active) {
        out[pix*3+0] = accr;
        out[pix*3+1] = accg;
        out[pix*3+2] = accb;
    }
}

extern "C" void kernel_launch(void* const* d_in, const int* in_sizes, int n_in,
                              void* d_out, int out_size, void* d_ws, size_t ws_size,
                              hipStream_t stream) {
    const float* means  = (const float*)d_in[0];
    const float* covs   = (const float*)d_in[1];
    const float* colors = (const float*)d_in[2];
    const float* opac   = (const float*)d_in[3];
    const float* K      = (const float*)d_in[4];
    const float* c2w    = (const float*)d_in[5];
    const int*   hp     = (const int*)d_in[6];
    const int*   wp     = (const int*)d_in[7];

    int N = in_sizes[0] / 3;   // 1024 (power of two; bitonic sort relies on it)

    char* ws = (char*)d_ws;
    GParam* params = (GParam*)ws;
    GParam* sorted = (GParam*)(ws + (size_t)N * sizeof(GParam));
    unsigned long long* keys = (unsigned long long*)(ws + 2ull * N * sizeof(GParam));
    int* countp = (int*)(ws + 2ull * N * sizeof(GParam) + (size_t)N * 8);

    gs_prep<<<(N + 255) / 256, 256, 0, stream>>>(means, covs, colors, opac, K, c2w,
                                                 hp, wp, params, keys, N);
    gs_sort_gather<<<1, N, 0, stream>>>(params, keys, sorted, countp);

    int npix = out_size / 3;
    gs_render<<<(npix + 255) / 256, 256, 0, stream>>>(sorted, countp, hp, wp, (float*)d_out);
}

// Round 2
// 62.551 us; speedup vs baseline: 3.4868x; 3.4868x over previous
//
#include <hip/hip_runtime.h>
#include <stdint.h>
#include <math.h>

#define NEAR_PLANE 0.0001f
#define MIN_COV    0.0001f
#define SIGMA_RAD  3.0f
#define ALPHA_MAX  0.999f

// 64-byte per-gaussian param block (16 floats) for clean float4 staging.
// float4 view: v0=(mx,my,ia,ib) v1=(ic,op,r,g) v2=(b,minx,maxx,miny) v3=(maxy,0,0,0)
struct GParam {
    float mx, my;
    float ia, ib, ic;
    float op;
    float r, g, b;
    float minx, maxx;
    float miny, maxy;
    float pad0, pad1, pad2;
};

__global__ void gs_prep(const float* __restrict__ means,
                        const float* __restrict__ covs,
                        const float* __restrict__ colors,
                        const float* __restrict__ opac,
                        const float* __restrict__ K,
                        const float* __restrict__ c2w,
                        const int* __restrict__ hp, const int* __restrict__ wp,
                        GParam* __restrict__ params,
                        unsigned long long* __restrict__ keys,
                        int N) {
    int i = blockIdx.x * blockDim.x + threadIdx.x;
    if (i >= N) return;
    float Wf = (float)(*wp), Hf = (float)(*hp);

    float R[3][3];
    #pragma unroll
    for (int r = 0; r < 3; ++r)
        #pragma unroll
        for (int c = 0; c < 3; ++c)
            R[r][c] = c2w[c * 4 + r];
    float ct0 = c2w[3], ct1 = c2w[7], ct2 = c2w[11];
    float t0 = -(R[0][0]*ct0 + R[0][1]*ct1 + R[0][2]*ct2);
    float t1 = -(R[1][0]*ct0 + R[1][1]*ct1 + R[1][2]*ct2);
    float t2 = -(R[2][0]*ct0 + R[2][1]*ct1 + R[2][2]*ct2);

    float m0 = means[i*3+0], m1 = means[i*3+1], m2 = means[i*3+2];
    float x = R[0][0]*m0 + R[0][1]*m1 + R[0][2]*m2 + t0;
    float y = R[1][0]*m0 + R[1][1]*m1 + R[1][2]*m2 + t1;
    float z = R[2][0]*m0 + R[2][1]*m1 + R[2][2]*m2 + t2;

    const float* C = covs + i * 9;
    float M[3][3], CC[3][3];
    #pragma unroll
    for (int r = 0; r < 3; ++r)
        #pragma unroll
        for (int c = 0; c < 3; ++c)
            M[r][c] = R[r][0]*C[0*3+c] + R[r][1]*C[1*3+c] + R[r][2]*C[2*3+c];
    #pragma unroll
    for (int r = 0; r < 3; ++r)
        #pragma unroll
        for (int c = 0; c < 3; ++c)
            CC[r][c] = M[r][0]*R[c][0] + M[r][1]*R[c][1] + M[r][2]*R[c][2];

    bool vis = z > NEAR_PLANE;
    float sz = vis ? z : 1.0f;
    float fx = K[0], fy = K[4], cx = K[2], cy = K[5];
    float mx = fx * x / sz + cx;
    float my = fy * y / sz + cy;

    float a0 = fx / sz, a2 = -fx * x / (sz * sz);
    float b1 = fy / sz, b2 = -fy * y / (sz * sz);
    float u0 = a0*CC[0][0] + a2*CC[2][0];
    float u1 = a0*CC[0][1] + a2*CC[2][1];
    float u2 = a0*CC[0][2] + a2*CC[2][2];
    float v1 = b1*CC[1][1] + b2*CC[2][1];
    float v2 = b1*CC[1][2] + b2*CC[2][2];
    float a = u0*a0 + u2*a2 + MIN_COV;
    float b = u1*b1 + u2*b2;
    float c = v1*b1 + v2*b2 + MIN_COV;

    float disc = sqrtf(fmaxf((a - c)*(a - c) + 4.0f*b*b, 0.0f));
    float lam  = fmaxf(0.5f*(a + c + disc), MIN_COV);
    float rad  = SIGMA_RAD * sqrtf(lam);
    float minx = floorf(mx - rad), maxx = ceilf(mx + rad);
    float miny = floorf(my - rad), maxy = ceilf(my + rad);
    bool overlap = vis && (maxx >= 0.0f) && (minx < Wf) && (maxy >= 0.0f) && (miny < Hf);

    float det = fmaxf(a*c - b*b, 1e-12f);
    GParam p;
    p.mx = mx; p.my = my;
    p.ia = c / det; p.ib = -b / det; p.ic = a / det;
    p.op = overlap ? opac[i] : 0.0f;
    p.r = colors[i*3+0]; p.g = colors[i*3+1]; p.b = colors[i*3+2];
    if (overlap) { p.minx = minx; p.maxx = maxx; p.miny = miny; p.maxy = maxy; }
    else         { p.minx = 1e30f; p.maxx = -1e30f; p.miny = 1e30f; p.maxy = -1e30f; }
    p.pad0 = p.pad1 = p.pad2 = 0.0f;
    params[i] = p;

    unsigned int zb = overlap ? __float_as_uint(z) : 0x7F800000u;
    keys[i] = ((unsigned long long)zb << 32) | (unsigned int)i;
}

// One block of 1024 threads: bitonic sort keys, gather params into depth order.
__global__ void gs_sort_gather(const GParam* __restrict__ params,
                               const unsigned long long* __restrict__ keys,
                               GParam* __restrict__ sorted,
                               int* __restrict__ countp) {
    __shared__ unsigned long long sk[1024];
    int tid = threadIdx.x;
    sk[tid] = keys[tid];
    __syncthreads();
    for (int k = 2; k <= 1024; k <<= 1) {
        for (int j = k >> 1; j > 0; j >>= 1) {
            int ixj = tid ^ j;
            if (ixj > tid) {
                unsigned long long A = sk[tid], B = sk[ixj];
                bool up = (tid & k) == 0;
                if ((A > B) == up) { sk[tid] = B; sk[ixj] = A; }
            }
            __syncthreads();
        }
    }
    unsigned long long key = sk[tid];
    int finite = ((unsigned int)(key >> 32)) < 0x7F800000u ? 1 : 0;
    int cnt = __syncthreads_count(finite);
    if (tid == 0) *countp = cnt;
    unsigned int idx = (unsigned int)(key & 0xFFFFFFFFu);
    const float4* src = (const float4*)(params + idx);
    float4*       dst = (float4*)(sorted + tid);
    dst[0] = src[0]; dst[1] = src[1]; dst[2] = src[2]; dst[3] = src[3];
}

// Tiled renderer: one 64-thread wave per 8x8 pixel tile per depth segment.
// Wave-parallel bbox cull of 64-gaussian chunks, stable ballot-compaction
// into LDS, then per-pixel compositing of survivors only.
__global__ __launch_bounds__(64) void gs_render_tiled(const GParam* __restrict__ sorted,
                                                      int W, int H, int segLen, int npix, int nseg,
                                                      float4* __restrict__ partial,
                                                      float* __restrict__ out) {
    __shared__ float4 sg[64 * 4];
    int tilesX = (W + 7) >> 3;
    int tile = blockIdx.x;
    int tx0 = (tile % tilesX) << 3, ty0 = (tile / tilesX) << 3;
    int lane = threadIdx.x;
    int px = tx0 + (lane & 7), py = ty0 + (lane >> 3);
    bool active = (px < W) && (py < H);
    float fpx = (float)px, fpy = (float)py;
    float tXmin = (float)tx0, tXmax = (float)(tx0 + 7 < W ? tx0 + 7 : W - 1);
    float tYmin = (float)ty0, tYmax = (float)(ty0 + 7 < H ? ty0 + 7 : H - 1);

    int seg = blockIdx.y;
    int base0 = seg * segLen;
    float T = 1.0f, accr = 0.0f, accg = 0.0f, accb = 0.0f;
    bool done = !active;
    int nchunk = segLen >> 6;

    for (int c = 0; c < nchunk; ++c) {
        int gbase = base0 + (c << 6);
        const float4* g = (const float4*)(sorted + gbase + lane);
        float4 v0 = g[0], v1 = g[1], v2 = g[2], v3 = g[3];
        // bbox: minx=v2.y maxx=v2.z miny=v2.w maxy=v3.x
        bool keep = !(v2.z < tXmin || v2.y > tXmax || v3.x < tYmin || v2.w > tYmax);
        unsigned long long mask = __ballot(keep);
        int pos = __popcll(mask & ((1ull << lane) - 1ull));
        int cnt = __popcll(mask);
        __syncthreads();
        if (keep) {
            float4* d = &sg[pos * 4];
            d[0] = v0; d[1] = v1; d[2] = v2; d[3] = v3;
        }
        __syncthreads();
        if (!done) {
            for (int gi = 0; gi < cnt; ++gi) {
                float4 l2 = sg[gi * 4 + 2];
                float gmaxy = sg[gi * 4 + 3].x;
                if (fpx < l2.y || fpx > l2.z || fpy < l2.w || fpy > gmaxy) continue;
                float4 l0 = sg[gi * 4 + 0], l1 = sg[gi * 4 + 1];
                float dx = fpx - l0.x, dy = fpy - l0.y;
                float q = l0.z * dx * dx + 2.0f * l0.w * dx * dy + l1.x * dy * dy;
                float w = __expf(-0.5f * q);
                float alpha = fminf(l1.y * w, ALPHA_MAX);
                float at = alpha * T;
                accr += at * l1.z; accg += at * l1.w; accb += at * l2.x;
                T *= (1.0f - alpha);
                if (T < 1e-6f) { done = true; break; }
            }
        }
    }
    if (active) {
        int pix = py * W + px;
        if (nseg == 1) {
            out[pix * 3 + 0] = accr;
            out[pix * 3 + 1] = accg;
            out[pix * 3 + 2] = accb;
        } else {
            partial[seg * npix + pix] = make_float4(accr, accg, accb, T);
        }
    }
}

__global__ __launch_bounds__(256) void gs_combine(const float4* __restrict__ partial,
                                                  float* __restrict__ out,
                                                  int npix, int nseg) {
    int pix = blockIdx.x * 256 + threadIdx.x;
    if (pix >= npix) return;
    float T = 1.0f, r = 0.0f, g = 0.0f, b = 0.0f;
    for (int s = 0; s < nseg; ++s) {
        float4 p = partial[s * npix + pix];
        r += T * p.x; g += T * p.y; b += T * p.z;
        T *= p.w;
    }
    out[pix * 3 + 0] = r;
    out[pix * 3 + 1] = g;
    out[pix * 3 + 2] = b;
}

extern "C" void kernel_launch(void* const* d_in, const int* in_sizes, int n_in,
                              void* d_out, int out_size, void* d_ws, size_t ws_size,
                              hipStream_t stream) {
    const float* means  = (const float*)d_in[0];
    const float* covs   = (const float*)d_in[1];
    const float* colors = (const float*)d_in[2];
    const float* opac   = (const float*)d_in[3];
    const float* K      = (const float*)d_in[4];
    const float* c2w    = (const float*)d_in[5];
    const int*   hp     = (const int*)d_in[6];
    const int*   wp     = (const int*)d_in[7];

    int N = in_sizes[0] / 3;       // 1024 (power of two)
    int npix = out_size / 3;
    int W = (int)(sqrt((double)npix) + 0.5);
    int H = npix / W;              // square image in this instance

    char* ws = (char*)d_ws;
    GParam* params = (GParam*)ws;                                    // 64 KB
    GParam* sorted = (GParam*)(ws + (size_t)N * sizeof(GParam));     // 64 KB
    unsigned long long* keys = (unsigned long long*)(ws + 2ull * N * sizeof(GParam)); // 8 KB
    int* countp = (int*)(ws + 2ull * N * sizeof(GParam) + (size_t)N * 8);
    size_t partialOff = 143360;    // 140 KB, past params/sorted/keys/count
    float4* partial = (float4*)(ws + partialOff);

    int nseg = 1;
    if (ws_size >= partialOff + 4ull * (size_t)npix * 16) nseg = 4;
    else if (ws_size >= partialOff + 2ull * (size_t)npix * 16) nseg = 2;
    int segLen = N / nseg;         // multiples of 64 for N=1024

    gs_prep<<<(N + 255) / 256, 256, 0, stream>>>(means, covs, colors, opac, K, c2w,
                                                 hp, wp, params, keys, N);
    gs_sort_gather<<<1, N, 0, stream>>>(params, keys, sorted, countp);

    int tilesX = (W + 7) / 8, tilesY = (H + 7) / 8;
    dim3 grid(tilesX * tilesY, nseg);
    gs_render_tiled<<<grid, 64, 0, stream>>>(sorted, W, H, segLen, npix, nseg,
                                             partial, (float*)d_out);
    if (nseg > 1)
        gs_combine<<<(npix + 255) / 256, 256, 0, stream>>>(partial, (float*)d_out, npix, nseg);
}

// Round 3
// 25.947 us; speedup vs baseline: 8.4057x; 2.4107x over previous
//
#include <hip/hip_runtime.h>
#include <stdint.h>
#include <math.h>

#define NEAR_PLANE 0.0001f
#define MIN_COV    0.0001f
#define SIGMA_RAD  3.0f
#define ALPHA_MAX  0.999f

// 48-byte per-gaussian param block (3 x float4):
// v0=(mx,my,ia,ib) v1=(ic,op,r,g) v2=(b, pack(minx,maxx), pack(miny,maxy), pad)
// bbox packed as int16 pairs (bbox values are whole numbers, clamped to i16).

__device__ inline unsigned long long shflx64(unsigned long long v, int j) {
    int lo = __shfl_xor((int)(unsigned)(v & 0xFFFFFFFFull), j, 64);
    int hi = __shfl_xor((int)(unsigned)(v >> 32), j, 64);
    return ((unsigned long long)(unsigned)hi << 32) | (unsigned)lo;
}

// One block of N=1024 threads: per-gaussian projection -> params (global),
// then hybrid bitonic sort of (zbits<<32 | idx) keys -> perm (global).
__global__ __launch_bounds__(1024) void gs_prep_sort(
        const float* __restrict__ means,
        const float* __restrict__ covs,
        const float* __restrict__ colors,
        const float* __restrict__ opac,
        const float* __restrict__ K,
        const float* __restrict__ c2w,
        const int* __restrict__ hp, const int* __restrict__ wp,
        float4* __restrict__ params,   // N * 3 float4
        int* __restrict__ perm,        // N
        int N) {
    int i = threadIdx.x;
    float Wf = (float)(*wp), Hf = (float)(*hp);

    float R[3][3];
    #pragma unroll
    for (int r = 0; r < 3; ++r)
        #pragma unroll
        for (int c = 0; c < 3; ++c)
            R[r][c] = c2w[c * 4 + r];
    float ct0 = c2w[3], ct1 = c2w[7], ct2 = c2w[11];
    float t0 = -(R[0][0]*ct0 + R[0][1]*ct1 + R[0][2]*ct2);
    float t1 = -(R[1][0]*ct0 + R[1][1]*ct1 + R[1][2]*ct2);
    float t2 = -(R[2][0]*ct0 + R[2][1]*ct1 + R[2][2]*ct2);

    float m0 = means[i*3+0], m1 = means[i*3+1], m2 = means[i*3+2];
    float x = R[0][0]*m0 + R[0][1]*m1 + R[0][2]*m2 + t0;
    float y = R[1][0]*m0 + R[1][1]*m1 + R[1][2]*m2 + t1;
    float z = R[2][0]*m0 + R[2][1]*m1 + R[2][2]*m2 + t2;

    const float* C = covs + i * 9;
    float M[3][3], CC[3][3];
    #pragma unroll
    for (int r = 0; r < 3; ++r)
        #pragma unroll
        for (int c = 0; c < 3; ++c)
            M[r][c] = R[r][0]*C[0*3+c] + R[r][1]*C[1*3+c] + R[r][2]*C[2*3+c];
    #pragma unroll
    for (int r = 0; r < 3; ++r)
        #pragma unroll
        for (int c = 0; c < 3; ++c)
            CC[r][c] = M[r][0]*R[c][0] + M[r][1]*R[c][1] + M[r][2]*R[c][2];

    bool vis = z > NEAR_PLANE;
    float sz = vis ? z : 1.0f;
    float fx = K[0], fy = K[4], cx = K[2], cy = K[5];
    float mx = fx * x / sz + cx;
    float my = fy * y / sz + cy;

    float a0 = fx / sz, a2 = -fx * x / (sz * sz);
    float b1 = fy / sz, b2 = -fy * y / (sz * sz);
    float u0 = a0*CC[0][0] + a2*CC[2][0];
    float u1 = a0*CC[0][1] + a2*CC[2][1];
    float u2 = a0*CC[0][2] + a2*CC[2][2];
    float v1 = b1*CC[1][1] + b2*CC[2][1];
    float v2 = b1*CC[1][2] + b2*CC[2][2];
    float a = u0*a0 + u2*a2 + MIN_COV;
    float b = u1*b1 + u2*b2;
    float c = v1*b1 + v2*b2 + MIN_COV;

    float disc = sqrtf(fmaxf((a - c)*(a - c) + 4.0f*b*b, 0.0f));
    float lam  = fmaxf(0.5f*(a + c + disc), MIN_COV);
    float rad  = SIGMA_RAD * sqrtf(lam);
    float minx = floorf(mx - rad), maxx = ceilf(mx + rad);
    float miny = floorf(my - rad), maxy = ceilf(my + rad);
    bool overlap = vis && (maxx >= 0.0f) && (minx < Wf) && (maxy >= 0.0f) && (miny < Hf);

    float det = fmaxf(a*c - b*b, 1e-12f);

    int mnx, mxx, mny, mxy;
    if (overlap) {
        mnx = (int)fmaxf(fminf(minx,  32767.0f), -32768.0f);
        mxx = (int)fmaxf(fminf(maxx,  32767.0f), -32768.0f);
        mny = (int)fmaxf(fminf(miny,  32767.0f), -32768.0f);
        mxy = (int)fmaxf(fminf(maxy,  32767.0f), -32768.0f);
    } else {
        mnx = 32767; mxx = -32768; mny = 32767; mxy = -32768;  // empty box
    }
    unsigned p01 = (unsigned)(mnx & 0xFFFF) | ((unsigned)(mxx & 0xFFFF) << 16);
    unsigned p23 = (unsigned)(mny & 0xFFFF) | ((unsigned)(mxy & 0xFFFF) << 16);

    float op = overlap ? opac[i] : 0.0f;
    params[i*3+0] = make_float4(mx, my, c / det, -b / det);
    params[i*3+1] = make_float4(a / det, op, colors[i*3+0], colors[i*3+1]);
    params[i*3+2] = make_float4(colors[i*3+2], __int_as_float((int)p01),
                                __int_as_float((int)p23), 0.0f);

    unsigned int zb = overlap ? __float_as_uint(z) : 0x7F800000u;
    unsigned long long key = ((unsigned long long)zb << 32) | (unsigned)i;

    // ---- bitonic sort: LDS exchange for j>=64, shfl_xor for j<64 ----
    __shared__ unsigned long long sk[1024];
    for (int k = 2; k <= N; k <<= 1) {
        int j = k >> 1;
        for (; j >= 64; j >>= 1) {
            sk[i] = key;
            __syncthreads();
            unsigned long long p = sk[i ^ j];
            __syncthreads();
            bool takeMin = (((i & j) == 0) == ((i & k) == 0));
            key = (takeMin == (key < p)) ? key : p;
        }
        for (; j >= 1; j >>= 1) {
            unsigned long long p = shflx64(key, j);
            bool takeMin = (((i & j) == 0) == ((i & k) == 0));
            key = (takeMin == (key < p)) ? key : p;
        }
    }
    perm[i] = (int)(key & 0xFFFFFFFFull);
}

// One 64-thread wave per 8x8 tile per depth segment. Wave-parallel bbox cull
// (int16 compares), stable ballot-compaction into LDS, branchless per-pixel
// compositing with per-chunk early-out. Next chunk register-prefetched.
__global__ __launch_bounds__(64) void gs_render_tiled(
        const float4* __restrict__ params,
        const int* __restrict__ perm,
        int W, int H, int segLen, int npix, int nseg,
        float4* __restrict__ partial,
        float* __restrict__ out) {
    __shared__ float4 sgv[64 * 3];
    int tilesX = (W + 7) >> 3;
    int tile = blockIdx.x;
    int tx0 = (tile % tilesX) << 3, ty0 = (tile / tilesX) << 3;
    int lane = threadIdx.x;
    int px = tx0 + (lane & 7), py = ty0 + (lane >> 3);
    bool active = (px < W) && (py < H);
    float fpx = (float)px, fpy = (float)py;
    int txMax = tx0 + 7, tyMax = ty0 + 7;

    int seg = blockIdx.y;
    int base0 = seg * segLen;
    float T = active ? 1.0f : 0.0f;
    float accr = 0.0f, accg = 0.0f, accb = 0.0f;
    int nchunk = segLen >> 6;

    // prefetch chunk 0
    int idx = perm[base0 + lane];
    float4 c0 = params[idx*3+0], c1 = params[idx*3+1], c2 = params[idx*3+2];

    for (int c = 0; c < nchunk; ++c) {
        float4 n0, n1, n2;
        if (c + 1 < nchunk) {
            int nidx = perm[base0 + (c + 1) * 64 + lane];
            n0 = params[nidx*3+0]; n1 = params[nidx*3+1]; n2 = params[nidx*3+2];
        }
        // tile-level cull on packed int16 bbox
        int bb01 = __float_as_int(c2.y), bb23 = __float_as_int(c2.z);
        int gmnx = (bb01 << 16) >> 16, gmxx = bb01 >> 16;
        int gmny = (bb23 << 16) >> 16, gmxy = bb23 >> 16;
        bool keep = (gmxx >= tx0) & (gmnx <= txMax) & (gmxy >= ty0) & (gmny <= tyMax);
        unsigned long long mask = __ballot(keep);
        int cnt = __popcll(mask);
        if (cnt) {
            int pos = __popcll(mask & ((1ull << lane) - 1ull));
            __syncthreads();
            if (keep) {
                sgv[pos*3+0] = c0; sgv[pos*3+1] = c1; sgv[pos*3+2] = c2;
            }
            __syncthreads();
            #pragma unroll 4
            for (int gi = 0; gi < cnt; ++gi) {
                float4 l0 = sgv[gi*3+0];
                float4 l1 = sgv[gi*3+1];
                float4 l2 = sgv[gi*3+2];
                int b01 = __float_as_int(l2.y), b23 = __float_as_int(l2.z);
                bool inside = (px >= ((b01 << 16) >> 16)) & (px <= (b01 >> 16))
                            & (py >= ((b23 << 16) >> 16)) & (py <= (b23 >> 16));
                float dx = fpx - l0.x, dy = fpy - l0.y;
                float q = fmaf(l0.z * dx, dx, fmaf(2.0f * l0.w * dx, dy, l1.x * dy * dy));
                float w = __expf(-0.5f * q);
                float alpha = inside ? fminf(l1.y * w, ALPHA_MAX) : 0.0f;
                float at = alpha * T;
                accr = fmaf(at, l1.z, accr);
                accg = fmaf(at, l1.w, accg);
                accb = fmaf(at, l2.x, accb);
                T = T - at;
            }
            if (__all(T < 1e-6f)) break;
        }
        c0 = n0; c1 = n1; c2 = n2;
    }
    if (active) {
        int pix = py * W + px;
        if (nseg == 1) {
            out[pix * 3 + 0] = accr;
            out[pix * 3 + 1] = accg;
            out[pix * 3 + 2] = accb;
        } else {
            partial[seg * npix + pix] = make_float4(accr, accg, accb, T);
        }
    }
}

__global__ __launch_bounds__(256) void gs_combine(const float4* __restrict__ partial,
                                                  float* __restrict__ out,
                                                  int npix, int nseg) {
    int pix = blockIdx.x * 256 + threadIdx.x;
    if (pix >= npix) return;
    float T = 1.0f, r = 0.0f, g = 0.0f, b = 0.0f;
    for (int s = 0; s < nseg; ++s) {
        float4 p = partial[s * npix + pix];
        r = fmaf(T, p.x, r); g = fmaf(T, p.y, g); b = fmaf(T, p.z, b);
        T *= p.w;
    }
    out[pix * 3 + 0] = r;
    out[pix * 3 + 1] = g;
    out[pix * 3 + 2] = b;
}

extern "C" void kernel_launch(void* const* d_in, const int* in_sizes, int n_in,
                              void* d_out, int out_size, void* d_ws, size_t ws_size,
                              hipStream_t stream) {
    const float* means  = (const float*)d_in[0];
    const float* covs   = (const float*)d_in[1];
    const float* colors = (const float*)d_in[2];
    const float* opac   = (const float*)d_in[3];
    const float* K      = (const float*)d_in[4];
    const float* c2w    = (const float*)d_in[5];
    const int*   hp     = (const int*)d_in[6];
    const int*   wp     = (const int*)d_in[7];

    int N = in_sizes[0] / 3;       // 1024 (power of two; sort relies on it)
    int npix = out_size / 3;
    int W = (int)(sqrt((double)npix) + 0.5);
    int H = npix / W;              // square image in this instance

    char* ws = (char*)d_ws;
    float4* params = (float4*)ws;                       // N*48 B = 48 KB
    int*    perm   = (int*)(ws + (size_t)N * 48);       // N*4 B
    size_t partialOff = ((size_t)N * 48 + (size_t)N * 4 + 255) & ~(size_t)255;
    float4* partial = (float4*)(ws + partialOff);

    int nseg = 1;
    if (ws_size >= partialOff + 8ull * (size_t)npix * 16) nseg = 8;
    else if (ws_size >= partialOff + 4ull * (size_t)npix * 16) nseg = 4;
    else if (ws_size >= partialOff + 2ull * (size_t)npix * 16) nseg = 2;
    int segLen = N / nseg;         // 128 for N=1024, nseg=8

    gs_prep_sort<<<1, N, 0, stream>>>(means, covs, colors, opac, K, c2w,
                                      hp, wp, params, perm, N);

    int tilesX = (W + 7) / 8, tilesY = (H + 7) / 8;
    dim3 grid(tilesX * tilesY, nseg);
    gs_render_tiled<<<grid, 64, 0, stream>>>(params, perm, W, H, segLen, npix, nseg,
                                             partial, (float*)d_out);
    if (nseg > 1)
        gs_combine<<<(npix + 255) / 256, 256, 0, stream>>>(partial, (float*)d_out, npix, nseg);
}

// Round 4
// 23.773 us; speedup vs baseline: 9.1744x; 1.0915x over previous
//
#include <hip/hip_runtime.h>
#include <stdint.h>
#include <math.h>

#define NEAR_PLANE 0.0001f
#define MIN_COV    0.0001f
#define SIGMA_RAD  3.0f
#define ALPHA_MAX  0.999f

// params: 3 x float4 per gaussian:
// v0=(mx,my,ia,ib) v1=(ic,op,r,g) v2=(b,_,_,_)
// cull records (SoA): zb[i] = float bits of z (inf if culled),
// bbox[i] = uint2 of packed s16 (minx,maxx),(miny,maxy); empty box if culled.

__global__ __launch_bounds__(256) void gs_prep(
        const float* __restrict__ means,
        const float* __restrict__ covs,
        const float* __restrict__ colors,
        const float* __restrict__ opac,
        const float* __restrict__ K,
        const float* __restrict__ c2w,
        const int* __restrict__ hp, const int* __restrict__ wp,
        float4* __restrict__ params,
        unsigned* __restrict__ zb,
        uint2* __restrict__ bbox,
        int N) {
    int i = blockIdx.x * blockDim.x + threadIdx.x;
    if (i >= N) return;
    float Wf = (float)(*wp), Hf = (float)(*hp);

    float R[3][3];
    #pragma unroll
    for (int r = 0; r < 3; ++r)
        #pragma unroll
        for (int c = 0; c < 3; ++c)
            R[r][c] = c2w[c * 4 + r];
    float ct0 = c2w[3], ct1 = c2w[7], ct2 = c2w[11];
    float t0 = -(R[0][0]*ct0 + R[0][1]*ct1 + R[0][2]*ct2);
    float t1 = -(R[1][0]*ct0 + R[1][1]*ct1 + R[1][2]*ct2);
    float t2 = -(R[2][0]*ct0 + R[2][1]*ct1 + R[2][2]*ct2);

    float m0 = means[i*3+0], m1 = means[i*3+1], m2 = means[i*3+2];
    float x = R[0][0]*m0 + R[0][1]*m1 + R[0][2]*m2 + t0;
    float y = R[1][0]*m0 + R[1][1]*m1 + R[1][2]*m2 + t1;
    float z = R[2][0]*m0 + R[2][1]*m1 + R[2][2]*m2 + t2;

    const float* C = covs + i * 9;
    float M[3][3], CC[3][3];
    #pragma unroll
    for (int r = 0; r < 3; ++r)
        #pragma unroll
        for (int c = 0; c < 3; ++c)
            M[r][c] = R[r][0]*C[0*3+c] + R[r][1]*C[1*3+c] + R[r][2]*C[2*3+c];
    #pragma unroll
    for (int r = 0; r < 3; ++r)
        #pragma unroll
        for (int c = 0; c < 3; ++c)
            CC[r][c] = M[r][0]*R[c][0] + M[r][1]*R[c][1] + M[r][2]*R[c][2];

    bool vis = z > NEAR_PLANE;
    float sz = vis ? z : 1.0f;
    float fx = K[0], fy = K[4], cx = K[2], cy = K[5];
    float mx = fx * x / sz + cx;
    float my = fy * y / sz + cy;

    float a0 = fx / sz, a2 = -fx * x / (sz * sz);
    float b1 = fy / sz, b2 = -fy * y / (sz * sz);
    float u0 = a0*CC[0][0] + a2*CC[2][0];
    float u1 = a0*CC[0][1] + a2*CC[2][1];
    float u2 = a0*CC[0][2] + a2*CC[2][2];
    float v1 = b1*CC[1][1] + b2*CC[2][1];
    float v2 = b1*CC[1][2] + b2*CC[2][2];
    float a = u0*a0 + u2*a2 + MIN_COV;
    float b = u1*b1 + u2*b2;
    float c = v1*b1 + v2*b2 + MIN_COV;

    float disc = sqrtf(fmaxf((a - c)*(a - c) + 4.0f*b*b, 0.0f));
    float lam  = fmaxf(0.5f*(a + c + disc), MIN_COV);
    float rad  = SIGMA_RAD * sqrtf(lam);
    float minx = floorf(mx - rad), maxx = ceilf(mx + rad);
    float miny = floorf(my - rad), maxy = ceilf(my + rad);
    bool overlap = vis && (maxx >= 0.0f) && (minx < Wf) && (maxy >= 0.0f) && (miny < Hf);

    float det = fmaxf(a*c - b*b, 1e-12f);

    int mnx, mxx, mny, mxy;
    if (overlap) {
        mnx = (int)fmaxf(fminf(minx,  32767.0f), -32768.0f);
        mxx = (int)fmaxf(fminf(maxx,  32767.0f), -32768.0f);
        mny = (int)fmaxf(fminf(miny,  32767.0f), -32768.0f);
        mxy = (int)fmaxf(fminf(maxy,  32767.0f), -32768.0f);
    } else {
        mnx = 32767; mxx = -32768; mny = 32767; mxy = -32768;  // empty
    }
    float op = overlap ? opac[i] : 0.0f;
    params[i*3+0] = make_float4(mx, my, c / det, -b / det);
    params[i*3+1] = make_float4(a / det, op, colors[i*3+0], colors[i*3+1]);
    params[i*3+2] = make_float4(colors[i*3+2], 0.0f, 0.0f, 0.0f);

    zb[i] = overlap ? __float_as_uint(z) : 0x7F800000u;
    bbox[i] = make_uint2((unsigned)(mnx & 0xFFFF) | ((unsigned)(mxx & 0xFFFF) << 16),
                         (unsigned)(mny & 0xFFFF) | ((unsigned)(mxy & 0xFFFF) << 16));
}

// One block (256 threads = 4 waves) per 8x8 tile.
// Phase 1: cooperative cull of all N gaussians -> survivor keys in LDS.
// Phase 2: LDS bitonic sort of keys (depth order == global stable order).
// Phase 3: gather survivor params into LDS.
// Phase 4: waves composite 4 contiguous depth ranges; in-LDS ordered merge.
__global__ __launch_bounds__(256) void gs_render(
        const float4* __restrict__ params,
        const unsigned* __restrict__ zb,
        const uint2* __restrict__ bbox,
        int W, int H, int N,
        float* __restrict__ out) {
    __shared__ unsigned long long sk[1024];
    __shared__ float4 sp[1024 * 3];
    __shared__ float4 s_part[4][64];
    __shared__ int s_cnt;

    int tid = threadIdx.x;
    int lane = tid & 63, wv = tid >> 6;
    int tilesX = (W + 7) >> 3;
    int tile = blockIdx.x;
    int tx0 = (tile % tilesX) << 3, ty0 = (tile / tilesX) << 3;
    int txMax = tx0 + 7, tyMax = ty0 + 7;

    if (tid == 0) s_cnt = 0;
    __syncthreads();

    // ---- cull ----
    for (int r = 0; r < N; r += 256) {
        int i = r + tid;
        bool keep = false;
        unsigned long long key = 0;
        if (i < N) {
            uint2 bb = bbox[i];
            int gmnx = ((int)bb.x << 16) >> 16, gmxx = (int)bb.x >> 16;
            int gmny = ((int)bb.y << 16) >> 16, gmxy = (int)bb.y >> 16;
            keep = (gmxx >= tx0) & (gmnx <= txMax) & (gmxy >= ty0) & (gmny <= tyMax);
            if (keep) key = ((unsigned long long)zb[i] << 32) | (unsigned)i;
        }
        unsigned long long m = __ballot(keep);
        int base = 0;
        if (lane == 0 && m) base = atomicAdd(&s_cnt, __popcll(m));
        base = __shfl(base, 0, 64);
        if (keep) {
            int pos = __popcll(m & ((1ull << lane) - 1ull));
            sk[base + pos] = key;
        }
    }
    __syncthreads();
    int S = s_cnt;

    // ---- pad + bitonic sort ----
    int pad = 1;
    while (pad < S) pad <<= 1;
    for (int i = S + tid; i < pad; i += 256) sk[i] = ~0ull;
    __syncthreads();
    for (int k = 2; k <= pad; k <<= 1) {
        for (int j = k >> 1; j > 0; j >>= 1) {
            for (int i = tid; i < pad; i += 256) {
                int ixj = i ^ j;
                if (ixj > i) {
                    unsigned long long A = sk[i], B = sk[ixj];
                    bool up = (i & k) == 0;
                    if ((A > B) == up) { sk[i] = B; sk[ixj] = A; }
                }
            }
            __syncthreads();
        }
    }

    // ---- gather survivor params ----
    for (int i = tid; i < S; i += 256) {
        int g = (int)(sk[i] & 0xFFFFFFFFull);
        sp[i*3+0] = params[g*3+0];
        sp[i*3+1] = params[g*3+1];
        sp[i*3+2] = params[g*3+2];
    }
    __syncthreads();

    // ---- composite: wave wv owns contiguous depth range ----
    int per = (S + 3) >> 2;
    int lo = wv * per, hi = min(S, lo + per);
    int px = tx0 + (lane & 7), py = ty0 + (lane >> 3);
    float fpx = (float)px, fpy = (float)py;
    float T = 1.0f, accr = 0.0f, accg = 0.0f, accb = 0.0f;
    for (int i = lo; i < hi; ++i) {
        float4 l0 = sp[i*3+0];
        float4 l1 = sp[i*3+1];
        float  cb = sp[i*3+2].x;
        float dx = fpx - l0.x, dy = fpy - l0.y;
        float q = fmaf(l0.z * dx, dx, fmaf(2.0f * l0.w * dx, dy, l1.x * dy * dy));
        float w = __expf(-0.5f * q);
        float alpha = fminf(l1.y * w, ALPHA_MAX);
        float at = alpha * T;
        accr = fmaf(at, l1.z, accr);
        accg = fmaf(at, l1.w, accg);
        accb = fmaf(at, cb, accb);
        T = T - at;
        if (__all(T < 1e-6f)) break;
    }
    s_part[wv][lane] = make_float4(accr, accg, accb, T);
    __syncthreads();

    if (wv == 0 && px < W && py < H) {
        float Tc = 1.0f, r = 0.0f, g = 0.0f, b = 0.0f;
        #pragma unroll
        for (int s = 0; s < 4; ++s) {
            float4 p = s_part[s][lane];
            r = fmaf(Tc, p.x, r);
            g = fmaf(Tc, p.y, g);
            b = fmaf(Tc, p.z, b);
            Tc *= p.w;
        }
        int pix = py * W + px;
        out[pix*3+0] = r;
        out[pix*3+1] = g;
        out[pix*3+2] = b;
    }
}

extern "C" void kernel_launch(void* const* d_in, const int* in_sizes, int n_in,
                              void* d_out, int out_size, void* d_ws, size_t ws_size,
                              hipStream_t stream) {
    const float* means  = (const float*)d_in[0];
    const float* covs   = (const float*)d_in[1];
    const float* colors = (const float*)d_in[2];
    const float* opac   = (const float*)d_in[3];
    const float* K      = (const float*)d_in[4];
    const float* c2w    = (const float*)d_in[5];
    const int*   hp     = (const int*)d_in[6];
    const int*   wp     = (const int*)d_in[7];

    int N = in_sizes[0] / 3;       // 1024 (<=1024 required by LDS sizing)
    int npix = out_size / 3;
    int W = (int)(sqrt((double)npix) + 0.5);
    int H = npix / W;              // square image in this instance

    char* ws = (char*)d_ws;
    float4*   params = (float4*)ws;                          // N*48 B
    unsigned* zbp    = (unsigned*)(ws + (size_t)N * 48);     // N*4 B
    uint2*    bboxp  = (uint2*)(ws + (size_t)N * 52);        // N*8 B

    gs_prep<<<(N + 255) / 256, 256, 0, stream>>>(means, covs, colors, opac, K, c2w,
                                                 hp, wp, params, zbp, bboxp, N);

    int tilesX = (W + 7) / 8, tilesY = (H + 7) / 8;
    gs_render<<<tilesX * tilesY, 256, 0, stream>>>(params, zbp, bboxp, W, H, N,
                                                   (float*)d_out);
}